// Round 1
// baseline (839.167 us; speedup 1.0000x reference)
//
#include <hip/hip_runtime.h>
#include <hip/hip_bf16.h>
#include <math.h>

#define NB 4096
#define NN 64
#define NM 4
#define NF 128
#define NOBS 64
#define ND 64
#define NH 4
#define NLAYER 2
#define NFF 128
#define NHID 64
#define NOUT 8
#define EPSC 1e-6f

typedef unsigned short ushort_t;

struct GParams {
    const float* x_anc; const float* g_anc; const float* x_nei; const float* ew_anc;
    const float* W_anc; const float* b_anc;
    const float* Wv_emb; const float* bv_emb; const float* Wv_val; const float* bv_val;
    const float* r_Win; const float* r_bin; const float* r_lng; const float* r_lnb;
    const float* r_W1; const float* r_b1; const float* r_W2; const float* r_b2;
    const float* r_Wview; const float* r_bview; const float* r_Wmode; const float* r_bmode;
    const float* log_tau;
    const float* L_Wq; const float* L_Wk; const float* L_Wv; const float* L_Wo;
    const float* L_ln1g; const float* L_ln1b; const float* L_ln2g; const float* L_ln2b;
    const float* L_Wf1; const float* L_bf1; const float* L_Wf2; const float* L_bf2;
    const float* p_lng; const float* p_lnb; const float* p_W1; const float* p_b1;
    const float* p_W2; const float* p_b2;
    float* out;
};

__device__ __forceinline__ float gelu_f(float x) {
    return 0.5f * x * (1.0f + erff(x * 0.7071067811865476f));
}
__device__ __forceinline__ float wsum64(float v) {
#pragma unroll
    for (int off = 32; off > 0; off >>= 1) v += __shfl_xor(v, off, 64);
    return v;
}
__device__ __forceinline__ float wmax64(float v) {
#pragma unroll
    for (int off = 32; off > 0; off >>= 1) v = fmaxf(v, __shfl_xor(v, off, 64));
    return v;
}
// exact bf16 <-> f32 bit helpers (same rounding as __float2bfloat16 path used before)
__device__ __forceinline__ float bf2f(ushort_t u) {
    union { unsigned int i; float f; } c; c.i = ((unsigned int)u) << 16; return c.f;
}
__device__ __forceinline__ ushort_t f2bf(float f) {
    __hip_bfloat16 h = __float2bfloat16(f);
    ushort_t u; __builtin_memcpy(&u, &h, 2); return u;
}

__global__ __launch_bounds__(256, 4)
void gora_fused(GParams P)
{
    const int b = blockIdx.x;
    const int t = threadIdx.x;
    const int lane = t & 63;
    const int wave = t >> 6;

    // ---- LDS ~40.4 KB -> 4 blocks/CU ----
    __shared__ alignas(16) char u1buf[NN * NF * 2];   // 16 KB: xsf (bf16) THEN hns (f32) after xsf is dead
    __shared__ alignas(16) char kbuf[NN * ND * 2];    // 8 KB  K  bf16, rows 128B, 16B-chunk XOR swizzle
    __shared__ alignas(16) char vbuf[NN * ND * 2];    // 8 KB  V^T bf16, rows 128B, 16B-chunk XOR swizzle
    __shared__ alignas(16) char scratch[4864];        // phase-unioned small buffers
    __shared__ float gate_s[NH][NN];
    __shared__ float pvc[NM][ND];
    __shared__ float xcur[ND];
    __shared__ float hfin[NHID];
    __shared__ float pi_s[NH][NM];
    __shared__ float pi_raw[NH * NM];
    __shared__ float beta_s[NH];
    __shared__ float winv[NM], wssum[NM];

    __hip_bfloat16* xsf = (__hip_bfloat16*)u1buf;     // phase 1: x_nei[b] bf16
    float (*hns)[ND]    = (float (*)[ND])u1buf;       // phase 2+: h_nei_shared fp32 (overlays xsf)

    // --- early-phase scratch layout (dead before layer loop) ---
    float* ew_s     = (float*)scratch;                // [NN*NM] raw masked ew
    float (*xw)[NF] = (float (*)[NF])(scratch + 1024);// [NM][NF]
    float* xa       = (float*)(scratch + 3072);       // [NF]
    float* ga       = (float*)(scratch + 3584);       // [NOBS]
    float (*hv)[ND] = (float (*)[ND])(scratch + 3840);// [NM][ND]
    float* sA       = (float*)(scratch + 3840);       // reuses hv (after pvc consumed it)
    float* sB       = (float*)(scratch + 4096);
    // --- layer-phase scratch layout ---
    float* qv     = (float*)scratch;                  // [ND]
    float* attn_f = (float*)(scratch + 256);          // [NH*NN], 16B aligned for float4 reads
    float* ctx_s  = (float*)(scratch + 1280);         // [ND]
    float* ffs    = (float*)(scratch + 1536);         // [NFF]
    // --- tail-phase scratch layout ---
    float* sAe = (float*)scratch;                     // [ND]
    float* sBe = (float*)(scratch + 512);             // [32]

    // ================= loads =================
    {
        float e = P.ew_anc[(size_t)b * NN * NM + t];   // 256 = N*M exactly
        ew_s[t] = (e > 0.0f) ? e : 0.0f;               // ew * (ew>0)
    }
    if (t < NF) xa[t] = P.x_anc[(size_t)b * NF + t];
    else if (t < NF + NOBS) ga[t - NF] = P.g_anc[(size_t)b * NOBS + (t - NF)];
    {
        const float4* xn4 = (const float4*)(P.x_nei + (size_t)b * NN * NF);
#pragma unroll
        for (int i = 0; i < 8; i++) {
            int i4 = t + i * 256;                      // 2048 float4 total
            float4 v4 = xn4[i4];
            __hip_bfloat162 p0, p1;
            p0.x = __float2bfloat16(v4.x); p0.y = __float2bfloat16(v4.y);
            p1.x = __float2bfloat16(v4.z); p1.y = __float2bfloat16(v4.w);
            __hip_bfloat162* dst = (__hip_bfloat162*)&xsf[i4 * 4];
            dst[0] = p0; dst[1] = p1;
        }
    }
    __syncthreads();

    // ======== view-weight norms (t<4) + h_anc (t in [64,128)) ========
    if (t < NM) {
        float s = 0.0f;
        for (int n = 0; n < NN; n++) s += ew_s[n * NM + t];
        float c = fmaxf(s, EPSC);
        winv[t]  = 1.0f / c;
        wssum[t] = s / c;
    }
    if (t >= 64 && t < 128) {
        int d = t - 64;
        float acc = P.b_anc[d];
        for (int f = 0; f < NF; f++) acc += xa[f] * P.W_anc[f * ND + d];
        xcur[d] = acc;                    // x = h_anc
    }
    __syncthreads();

    // ======== xw[m][f] = sum_n w[m,n]*x_nei[n,f]  AND  h_nei accumulate (regs) ========
    {
        int f = t & (NF - 1);
        int m0 = t >> 7;
        float a0 = 0.f, a1 = 0.f;
        for (int n = 0; n < NN; n++) {
            float xv = __bfloat162float(xsf[n * NF + f]);
            a0 += ew_s[n * NM + m0] * xv;
            a1 += ew_s[n * NM + m0 + 2] * xv;
        }
        xw[m0][f]     = a0 * winv[m0];
        xw[m0 + 2][f] = a1 * winv[m0 + 2];
    }
    float hacc[16];
    {
        const int d = lane;
        const int n0 = wave * 16;
        float bias = P.bv_emb[d];         // m = 0
#pragma unroll
        for (int i = 0; i < 16; i++) hacc[i] = bias;
        const float* W0 = P.Wv_emb;       // m = 0 block
        for (int ft = 0; ft < NF; ft += 8) {
            float w0r[8];
#pragma unroll
            for (int j = 0; j < 8; j++) w0r[j] = W0[(ft + j) * ND + d];
#pragma unroll
            for (int i = 0; i < 16; i++) {
                const float4 xr = *(const float4*)&xsf[(n0 + i) * NF + ft]; // 8 bf16
                const __hip_bfloat162* xp = (const __hip_bfloat162*)&xr;
#pragma unroll
                for (int j = 0; j < 4; j++) {
                    hacc[i] += __bfloat162float(xp[j].x) * w0r[2 * j];
                    hacc[i] += __bfloat162float(xp[j].y) * w0r[2 * j + 1];
                }
            }
        }
    }
    __syncthreads();   // all xsf reads done; xw visible
    {
        const int d = lane;
        const int n0 = wave * 16;
#pragma unroll
        for (int i = 0; i < 16; i++) hns[n0 + i][d] = hacc[i];   // overlays xsf
    }

    // ======== per_view_ctx: hv = xw@Wv_emb[m] + s*bv_emb ========
    {
        int m = wave, d = lane;
        float acc = wssum[m] * P.bv_emb[m * ND + d];
        const float* We = P.Wv_emb + (size_t)m * NF * ND;
        for (int f = 0; f < NF; f++) acc += xw[m][f] * We[f * ND + d];
        hv[m][d] = acc;
    }
    __syncthreads();
    {
        int m = wave, d = lane;
        float acc = wssum[m] * P.bv_val[m * ND + d];
        const float* Wv = P.Wv_val + (size_t)m * ND * ND;
        for (int k = 0; k < ND; k++) acc += hv[m][k] * Wv[k * ND + d];
        pvc[m][d] = acc;
    }
    __syncthreads();

    // ======== ctx_vec + r-MLP ========
    if (t < ND) sA[t] = 0.25f * (pvc[0][t] + pvc[1][t] + pvc[2][t] + pvc[3][t]);
    __syncthreads();
    if (t < NHID) {
        float acc = P.r_bin[t];
        for (int f = 0; f < NOBS; f++) acc += ga[f] * P.r_Win[f * NHID + t];
        for (int f = 0; f < ND;   f++) acc += sA[f] * P.r_Win[(NOBS + f) * NHID + t];
        float mean = wsum64(acc) * (1.0f / 64.0f);
        float dv = acc - mean;
        float var = wsum64(dv * dv) * (1.0f / 64.0f);
        float xln = dv * rsqrtf(var + 1e-5f) * P.r_lng[t] + P.r_lnb[t];
        sB[t] = gelu_f(xln);
    }
    __syncthreads();
    if (t < NHID) {
        float acc = P.r_b1[t];
        for (int k = 0; k < NHID; k++) acc += sB[k] * P.r_W1[k * NHID + t];
        sA[t] = gelu_f(acc);
    }
    __syncthreads();
    if (t < NHID) {
        float acc = P.r_b2[t];
        for (int k = 0; k < NHID; k++) acc += sA[k] * P.r_W2[k * NHID + t];
        hfin[t] = gelu_f(acc);
    }
    __syncthreads();

    // ======== pi (softmax over views), beta ========
    if (t < NH * NM) {
        int h = t >> 2, mm = t & 3;
        float acc = P.r_bview[h * NM + mm];
        for (int k = 0; k < NHID; k++) acc += hfin[k] * P.r_Wview[(h * NHID + k) * NM + mm];
        pi_raw[t] = acc;
    }
    if (t >= 64 && t < 64 + NH) {
        int h = t - 64;
        float acc = P.r_bmode[h];
        for (int k = 0; k < NHID; k++) acc += hfin[k] * P.r_Wmode[h * NHID + k];
        beta_s[h] = 1.0f / (1.0f + expf(-acc));
    }
    __syncthreads();
    if (t < NH) {
        float mx = -1e30f;
        for (int mm = 0; mm < NM; mm++) mx = fmaxf(mx, pi_raw[t * NM + mm]);
        float s = 0.f, e[NM];
        for (int mm = 0; mm < NM; mm++) { e[mm] = expf(pi_raw[t * NM + mm] - mx); s += e[mm]; }
        for (int mm = 0; mm < NM; mm++) pi_s[t][mm] = e[mm] / s;
    }
    __syncthreads();

    // ======== gate[h][n] = log(sum_m pi[h,m]*ew_raw[n,m] + EPS)  (last reader of ew_s) ========
    {
        int h = wave, n = lane;
        float wv = 0.f;
        for (int mm = 0; mm < NM; mm++) wv += pi_s[h][mm] * ew_s[n * NM + mm];
        gate_s[h][n] = logf(wv + EPSC);
    }
    __syncthreads();

    // ======== attention + FF layers ========
    const float inv_tau_scale = 0.25f / expf(P.log_tau[wave]);  // scale=1/sqrt(16)
    for (int l = 0; l < NLAYER; l++) {
        const float* Wq  = P.L_Wq  + l * ND * ND;
        const float* Wk  = P.L_Wk  + l * ND * ND;
        const float* Wvv = P.L_Wv  + l * ND * ND;
        const float* Wo  = P.L_Wo  + l * ND * ND;
        const float* ln1g = P.L_ln1g + l * ND;
        const float* ln1b = P.L_ln1b + l * ND;
        const float* ln2g = P.L_ln2g + l * ND;
        const float* ln2b = P.L_ln2b + l * ND;
        const float* Wf1 = P.L_Wf1 + l * ND * NFF;
        const float* bf1 = P.L_bf1 + l * NFF;
        const float* Wf2 = P.L_Wf2 + l * NFF * ND;
        const float* bf2 = P.L_bf2 + l * ND;

        if (t < ND) {
            float acc = 0.f;
            for (int k = 0; k < ND; k++) acc += xcur[k] * Wq[k * ND + t];
            qv[t] = acc;
        }
        // K/V projections from h_nei_shared (no bias in reference)
        {
            const int d = lane;
            const int n0 = wave * 16;
            float acck[16], accv[16];
#pragma unroll
            for (int i = 0; i < 16; i++) { acck[i] = 0.f; accv[i] = 0.f; }
            for (int kt = 0; kt < ND; kt += 4) {
                float wk[4], wv[4];
#pragma unroll
                for (int j = 0; j < 4; j++) {
                    wk[j] = Wk[(kt + j) * ND + d];
                    wv[j] = Wvv[(kt + j) * ND + d];
                }
#pragma unroll
                for (int i = 0; i < 16; i++) {
                    const float4 hr = *(const float4*)&hns[n0 + i][kt];
                    acck[i] += hr.x * wk[0] + hr.y * wk[1] + hr.z * wk[2] + hr.w * wk[3];
                    accv[i] += hr.x * wv[0] + hr.y * wv[1] + hr.z * wv[2] + hr.w * wv[3];
                }
            }
            // K row-major [n][d], 16B-chunk swizzle: chunk c of row n lives at c^(n&7)
            const int cK = d >> 3;
            const int sK = d & 7;
#pragma unroll
            for (int i = 0; i < 16; i++) {
                int n = n0 + i;
                ushort_t* kp = (ushort_t*)(kbuf + n * 128 + (((cK ^ (n & 7)) << 4)));
                kp[sK] = f2bf(acck[i]);
            }
            // V transposed [d][n], packed 8xbf16 stores, chunk swizzle: chunk c of row d at c^(d&7)
            union { ushort_t u[8]; uint4 q; } pk0, pk1;
#pragma unroll
            for (int j = 0; j < 8; j++) { pk0.u[j] = f2bf(accv[j]); pk1.u[j] = f2bf(accv[j + 8]); }
            char* rowv = vbuf + d * 128;
            *(uint4*)(rowv + (((2 * wave)     ^ (d & 7)) << 4)) = pk0.q;
            *(uint4*)(rowv + (((2 * wave + 1) ^ (d & 7)) << 4)) = pk1.q;
        }
        __syncthreads();
        // scores + softmax over n (one head per wave) — K read as 2x b128
        {
            const int h = wave, n = lane;
            const float4 q0 = *(const float4*)&qv[h * 16 + 0];
            const float4 q1 = *(const float4*)&qv[h * 16 + 4];
            const float4 q2 = *(const float4*)&qv[h * 16 + 8];
            const float4 q3 = *(const float4*)&qv[h * 16 + 12];
            const char* rowk = kbuf + n * 128;
            uint4 ka = *(const uint4*)(rowk + (((2 * h)     ^ (n & 7)) << 4));
            uint4 kb = *(const uint4*)(rowk + (((2 * h + 1) ^ (n & 7)) << 4));
            const ushort_t* ua = (const ushort_t*)&ka;
            const ushort_t* ub = (const ushort_t*)&kb;
            float s = q0.x * bf2f(ua[0]) + q0.y * bf2f(ua[1]) + q0.z * bf2f(ua[2]) + q0.w * bf2f(ua[3])
                    + q1.x * bf2f(ua[4]) + q1.y * bf2f(ua[5]) + q1.z * bf2f(ua[6]) + q1.w * bf2f(ua[7])
                    + q2.x * bf2f(ub[0]) + q2.y * bf2f(ub[1]) + q2.z * bf2f(ub[2]) + q2.w * bf2f(ub[3])
                    + q3.x * bf2f(ub[4]) + q3.y * bf2f(ub[5]) + q3.z * bf2f(ub[6]) + q3.w * bf2f(ub[7]);
            s = s * inv_tau_scale + gate_s[h][n];
            float mx = wmax64(s);
            float e = expf(s - mx);
            float se = wsum64(e);
            attn_f[h * NN + n] = e / se;
        }
        __syncthreads();
        // PV: lane t owns output dim t; V^T row read as 8x b128
        if (t < ND) {
            const int h = t >> 4;
            const float* attn_h = attn_f + h * NN;
            const char* rowv = vbuf + t * 128;
            float acc = 0.f;
#pragma unroll
            for (int c = 0; c < 8; c++) {
                uint4 vq = *(const uint4*)(rowv + (((c ^ (t & 7))) << 4));
                const ushort_t* u = (const ushort_t*)&vq;
                float4 a0 = *(const float4*)&attn_h[c * 8];
                float4 a1 = *(const float4*)&attn_h[c * 8 + 4];
                acc += a0.x * bf2f(u[0]) + a0.y * bf2f(u[1]) + a0.z * bf2f(u[2]) + a0.w * bf2f(u[3])
                     + a1.x * bf2f(u[4]) + a1.y * bf2f(u[5]) + a1.z * bf2f(u[6]) + a1.w * bf2f(u[7]);
            }
            ctx_s[t] = acc;
        }
        __syncthreads();
        if (t < ND) {
            float acc = 0.f;
            for (int c = 0; c < ND; c++) acc += ctx_s[c] * Wo[c * ND + t];
            float xv = xcur[t] + acc;
            float mean = wsum64(xv) * (1.0f / 64.0f);
            float dv = xv - mean;
            float var = wsum64(dv * dv) * (1.0f / 64.0f);
            xcur[t] = dv * rsqrtf(var + 1e-5f) * ln1g[t] + ln1b[t];
        }
        __syncthreads();
        if (t < NFF) {
            float acc = bf1[t];
            for (int d = 0; d < ND; d++) acc += xcur[d] * Wf1[d * NFF + t];
            ffs[t] = gelu_f(acc);
        }
        __syncthreads();
        if (t < ND) {
            float acc = bf2[t];
            for (int j = 0; j < NFF; j++) acc += ffs[j] * Wf2[j * ND + t];
            float xv = xcur[t] + acc;
            float mean = wsum64(xv) * (1.0f / 64.0f);
            float dv = xv - mean;
            float var = wsum64(dv * dv) * (1.0f / 64.0f);
            xcur[t] = dv * rsqrtf(var + 1e-5f) * ln2g[t] + ln2b[t];
        }
        __syncthreads();
    }

    // ======== blended + final head ========
    if (t < ND) {
        float acc = 0.f;
#pragma unroll
        for (int h = 0; h < NH; h++) {
            float iso = 0.f;
#pragma unroll
            for (int mm = 0; mm < NM; mm++) iso += pi_s[h][mm] * pvc[mm][t];
            acc += (1.0f - beta_s[h]) * iso + beta_s[h] * xcur[t];
        }
        float bl = acc * 0.25f;
        float mean = wsum64(bl) * (1.0f / 64.0f);
        float dv = bl - mean;
        float var = wsum64(dv * dv) * (1.0f / 64.0f);
        sAe[t] = dv * rsqrtf(var + 1e-5f) * P.p_lng[t] + P.p_lnb[t];
    }
    __syncthreads();
    if (t < 32) {
        float acc = P.p_b1[t];
        for (int d = 0; d < ND; d++) acc += sAe[d] * P.p_W1[d * 32 + t];
        sBe[t] = gelu_f(acc);
    }
    __syncthreads();
    if (t < NOUT) {
        float acc = P.p_b2[t];
        for (int j = 0; j < 32; j++) acc += sBe[j] * P.p_W2[j * NOUT + t];
        P.out[(size_t)b * NOUT + t] = acc;
    }
}

extern "C" void kernel_launch(void* const* d_in, const int* in_sizes, int n_in,
                              void* d_out, int out_size, void* d_ws, size_t ws_size,
                              hipStream_t stream)
{
    (void)in_sizes; (void)n_in; (void)d_ws; (void)ws_size; (void)out_size;
    GParams P;
    P.x_anc   = (const float*)d_in[0];
    P.g_anc   = (const float*)d_in[1];
    P.x_nei   = (const float*)d_in[2];
    P.ew_anc  = (const float*)d_in[3];
    P.W_anc   = (const float*)d_in[4];
    P.b_anc   = (const float*)d_in[5];
    P.Wv_emb  = (const float*)d_in[6];
    P.bv_emb  = (const float*)d_in[7];
    P.Wv_val  = (const float*)d_in[8];
    P.bv_val  = (const float*)d_in[9];
    P.r_Win   = (const float*)d_in[10];
    P.r_bin   = (const float*)d_in[11];
    P.r_lng   = (const float*)d_in[12];
    P.r_lnb   = (const float*)d_in[13];
    P.r_W1    = (const float*)d_in[14];
    P.r_b1    = (const float*)d_in[15];
    P.r_W2    = (const float*)d_in[16];
    P.r_b2    = (const float*)d_in[17];
    P.r_Wview = (const float*)d_in[18];
    P.r_bview = (const float*)d_in[19];
    P.r_Wmode = (const float*)d_in[20];
    P.r_bmode = (const float*)d_in[21];
    P.log_tau = (const float*)d_in[22];
    P.L_Wq    = (const float*)d_in[23];
    P.L_Wk    = (const float*)d_in[24];
    P.L_Wv    = (const float*)d_in[25];
    P.L_Wo    = (const float*)d_in[26];
    P.L_ln1g  = (const float*)d_in[27];
    P.L_ln1b  = (const float*)d_in[28];
    P.L_ln2g  = (const float*)d_in[29];
    P.L_ln2b  = (const float*)d_in[30];
    P.L_Wf1   = (const float*)d_in[31];
    P.L_bf1   = (const float*)d_in[32];
    P.L_Wf2   = (const float*)d_in[33];
    P.L_bf2   = (const float*)d_in[34];
    P.p_lng   = (const float*)d_in[35];
    P.p_lnb   = (const float*)d_in[36];
    P.p_W1    = (const float*)d_in[37];
    P.p_b1    = (const float*)d_in[38];
    P.p_W2    = (const float*)d_in[39];
    P.p_b2    = (const float*)d_in[40];
    P.out     = (float*)d_out;
    hipLaunchKernelGGL(gora_fused, dim3(NB), dim3(256), 0, stream, P);
}

// Round 2
// 784.462 us; speedup vs baseline: 1.0697x; 1.0697x over previous
//
#include <hip/hip_runtime.h>
#include <hip/hip_bf16.h>
#include <math.h>

#define NB 4096
#define NN 64
#define NM 4
#define NF 128
#define NOBS 64
#define ND 64
#define NH 4
#define NLAYER 2
#define NFF 128
#define NHID 64
#define NOUT 8
#define EPSC 1e-6f

typedef unsigned short ushort_t;

struct GParams {
    const float* x_anc; const float* g_anc; const float* x_nei; const float* ew_anc;
    const float* W_anc; const float* b_anc;
    const float* Wv_emb; const float* bv_emb; const float* Wv_val; const float* bv_val;
    const float* r_Win; const float* r_bin; const float* r_lng; const float* r_lnb;
    const float* r_W1; const float* r_b1; const float* r_W2; const float* r_b2;
    const float* r_Wview; const float* r_bview; const float* r_Wmode; const float* r_bmode;
    const float* log_tau;
    const float* L_Wq; const float* L_Wk; const float* L_Wv; const float* L_Wo;
    const float* L_ln1g; const float* L_ln1b; const float* L_ln2g; const float* L_ln2b;
    const float* L_Wf1; const float* L_bf1; const float* L_Wf2; const float* L_bf2;
    const float* p_lng; const float* p_lnb; const float* p_W1; const float* p_b1;
    const float* p_W2; const float* p_b2;
    float* out;
};

__device__ __forceinline__ float gelu_f(float x) {
    return 0.5f * x * (1.0f + erff(x * 0.7071067811865476f));
}
__device__ __forceinline__ float wsum64(float v) {
#pragma unroll
    for (int off = 32; off > 0; off >>= 1) v += __shfl_xor(v, off, 64);
    return v;
}
__device__ __forceinline__ float wmax64(float v) {
#pragma unroll
    for (int off = 32; off > 0; off >>= 1) v = fmaxf(v, __shfl_xor(v, off, 64));
    return v;
}
// exact bf16 <-> f32 bit helpers (same rounding as __float2bfloat16 path used before)
__device__ __forceinline__ float bf2f(ushort_t u) {
    union { unsigned int i; float f; } c; c.i = ((unsigned int)u) << 16; return c.f;
}
__device__ __forceinline__ ushort_t f2bf(float f) {
    __hip_bfloat16 h = __float2bfloat16(f);
    ushort_t u; __builtin_memcpy(&u, &h, 2); return u;
}

// NOTE: min-waves arg MUST stay at 2. (256,4) clamps the allocator to 64 VGPRs
// and spills hacc/acck/accv to scratch: WRITE_SIZE exploded 128KB -> 45MB and
// dur regressed 491 -> 662 us (round 1). LDS (40448B) already caps occupancy
// at 4 blocks/CU, so (256,2) keeps the occupancy win without spills.
__global__ __launch_bounds__(256, 2)
void gora_fused(GParams P)
{
    const int b = blockIdx.x;
    const int t = threadIdx.x;
    const int lane = t & 63;
    const int wave = t >> 6;

    // ---- LDS ~40.4 KB -> 4 blocks/CU ----
    __shared__ alignas(16) char u1buf[NN * NF * 2];   // 16 KB: xsf (bf16) THEN hns (f32) after xsf is dead
    __shared__ alignas(16) char kbuf[NN * ND * 2];    // 8 KB  K  bf16, rows 128B, 16B-chunk XOR swizzle
    __shared__ alignas(16) char vbuf[NN * ND * 2];    // 8 KB  V^T bf16, rows 128B, 16B-chunk XOR swizzle
    __shared__ alignas(16) char scratch[4864];        // phase-unioned small buffers
    __shared__ float gate_s[NH][NN];
    __shared__ float pvc[NM][ND];
    __shared__ float xcur[ND];
    __shared__ float hfin[NHID];
    __shared__ float pi_s[NH][NM];
    __shared__ float pi_raw[NH * NM];
    __shared__ float beta_s[NH];
    __shared__ float winv[NM], wssum[NM];

    __hip_bfloat16* xsf = (__hip_bfloat16*)u1buf;     // phase 1: x_nei[b] bf16
    float (*hns)[ND]    = (float (*)[ND])u1buf;       // phase 2+: h_nei_shared fp32 (overlays xsf)

    // --- early-phase scratch layout (dead before layer loop) ---
    float* ew_s     = (float*)scratch;                // [NN*NM] raw masked ew
    float (*xw)[NF] = (float (*)[NF])(scratch + 1024);// [NM][NF]
    float* xa       = (float*)(scratch + 3072);       // [NF]
    float* ga       = (float*)(scratch + 3584);       // [NOBS]
    float (*hv)[ND] = (float (*)[ND])(scratch + 3840);// [NM][ND]
    float* sA       = (float*)(scratch + 3840);       // reuses hv (after pvc consumed it)
    float* sB       = (float*)(scratch + 4096);
    // --- layer-phase scratch layout ---
    float* qv     = (float*)scratch;                  // [ND]
    float* attn_f = (float*)(scratch + 256);          // [NH*NN], 16B aligned for float4 reads
    float* ctx_s  = (float*)(scratch + 1280);         // [ND]
    float* ffs    = (float*)(scratch + 1536);         // [NFF]
    // --- tail-phase scratch layout ---
    float* sAe = (float*)scratch;                     // [ND]
    float* sBe = (float*)(scratch + 512);             // [32]

    // ================= loads =================
    {
        float e = P.ew_anc[(size_t)b * NN * NM + t];   // 256 = N*M exactly
        ew_s[t] = (e > 0.0f) ? e : 0.0f;               // ew * (ew>0)
    }
    if (t < NF) xa[t] = P.x_anc[(size_t)b * NF + t];
    else if (t < NF + NOBS) ga[t - NF] = P.g_anc[(size_t)b * NOBS + (t - NF)];
    {
        const float4* xn4 = (const float4*)(P.x_nei + (size_t)b * NN * NF);
#pragma unroll
        for (int i = 0; i < 8; i++) {
            int i4 = t + i * 256;                      // 2048 float4 total
            float4 v4 = xn4[i4];
            __hip_bfloat162 p0, p1;
            p0.x = __float2bfloat16(v4.x); p0.y = __float2bfloat16(v4.y);
            p1.x = __float2bfloat16(v4.z); p1.y = __float2bfloat16(v4.w);
            __hip_bfloat162* dst = (__hip_bfloat162*)&xsf[i4 * 4];
            dst[0] = p0; dst[1] = p1;
        }
    }
    __syncthreads();

    // ======== view-weight norms (t<4) + h_anc (t in [64,128)) ========
    if (t < NM) {
        float s = 0.0f;
        for (int n = 0; n < NN; n++) s += ew_s[n * NM + t];
        float c = fmaxf(s, EPSC);
        winv[t]  = 1.0f / c;
        wssum[t] = s / c;
    }
    if (t >= 64 && t < 128) {
        int d = t - 64;
        float acc = P.b_anc[d];
        for (int f = 0; f < NF; f++) acc += xa[f] * P.W_anc[f * ND + d];
        xcur[d] = acc;                    // x = h_anc
    }
    __syncthreads();

    // ======== xw[m][f] = sum_n w[m,n]*x_nei[n,f]  AND  h_nei accumulate (regs) ========
    {
        int f = t & (NF - 1);
        int m0 = t >> 7;
        float a0 = 0.f, a1 = 0.f;
        for (int n = 0; n < NN; n++) {
            float xv = __bfloat162float(xsf[n * NF + f]);
            a0 += ew_s[n * NM + m0] * xv;
            a1 += ew_s[n * NM + m0 + 2] * xv;
        }
        xw[m0][f]     = a0 * winv[m0];
        xw[m0 + 2][f] = a1 * winv[m0 + 2];
    }
    float hacc[16];
    {
        const int d = lane;
        const int n0 = wave * 16;
        float bias = P.bv_emb[d];         // m = 0
#pragma unroll
        for (int i = 0; i < 16; i++) hacc[i] = bias;
        const float* W0 = P.Wv_emb;       // m = 0 block
        for (int ft = 0; ft < NF; ft += 8) {
            float w0r[8];
#pragma unroll
            for (int j = 0; j < 8; j++) w0r[j] = W0[(ft + j) * ND + d];
#pragma unroll
            for (int i = 0; i < 16; i++) {
                const float4 xr = *(const float4*)&xsf[(n0 + i) * NF + ft]; // 8 bf16
                const __hip_bfloat162* xp = (const __hip_bfloat162*)&xr;
#pragma unroll
                for (int j = 0; j < 4; j++) {
                    hacc[i] += __bfloat162float(xp[j].x) * w0r[2 * j];
                    hacc[i] += __bfloat162float(xp[j].y) * w0r[2 * j + 1];
                }
            }
        }
    }
    __syncthreads();   // all xsf reads done; xw visible
    {
        const int d = lane;
        const int n0 = wave * 16;
#pragma unroll
        for (int i = 0; i < 16; i++) hns[n0 + i][d] = hacc[i];   // overlays xsf
    }

    // ======== per_view_ctx: hv = xw@Wv_emb[m] + s*bv_emb ========
    {
        int m = wave, d = lane;
        float acc = wssum[m] * P.bv_emb[m * ND + d];
        const float* We = P.Wv_emb + (size_t)m * NF * ND;
        for (int f = 0; f < NF; f++) acc += xw[m][f] * We[f * ND + d];
        hv[m][d] = acc;
    }
    __syncthreads();
    {
        int m = wave, d = lane;
        float acc = wssum[m] * P.bv_val[m * ND + d];
        const float* Wv = P.Wv_val + (size_t)m * ND * ND;
        for (int k = 0; k < ND; k++) acc += hv[m][k] * Wv[k * ND + d];
        pvc[m][d] = acc;
    }
    __syncthreads();

    // ======== ctx_vec + r-MLP ========
    if (t < ND) sA[t] = 0.25f * (pvc[0][t] + pvc[1][t] + pvc[2][t] + pvc[3][t]);
    __syncthreads();
    if (t < NHID) {
        float acc = P.r_bin[t];
        for (int f = 0; f < NOBS; f++) acc += ga[f] * P.r_Win[f * NHID + t];
        for (int f = 0; f < ND;   f++) acc += sA[f] * P.r_Win[(NOBS + f) * NHID + t];
        float mean = wsum64(acc) * (1.0f / 64.0f);
        float dv = acc - mean;
        float var = wsum64(dv * dv) * (1.0f / 64.0f);
        float xln = dv * rsqrtf(var + 1e-5f) * P.r_lng[t] + P.r_lnb[t];
        sB[t] = gelu_f(xln);
    }
    __syncthreads();
    if (t < NHID) {
        float acc = P.r_b1[t];
        for (int k = 0; k < NHID; k++) acc += sB[k] * P.r_W1[k * NHID + t];
        sA[t] = gelu_f(acc);
    }
    __syncthreads();
    if (t < NHID) {
        float acc = P.r_b2[t];
        for (int k = 0; k < NHID; k++) acc += sA[k] * P.r_W2[k * NHID + t];
        hfin[t] = gelu_f(acc);
    }
    __syncthreads();

    // ======== pi (softmax over views), beta ========
    if (t < NH * NM) {
        int h = t >> 2, mm = t & 3;
        float acc = P.r_bview[h * NM + mm];
        for (int k = 0; k < NHID; k++) acc += hfin[k] * P.r_Wview[(h * NHID + k) * NM + mm];
        pi_raw[t] = acc;
    }
    if (t >= 64 && t < 64 + NH) {
        int h = t - 64;
        float acc = P.r_bmode[h];
        for (int k = 0; k < NHID; k++) acc += hfin[k] * P.r_Wmode[h * NHID + k];
        beta_s[h] = 1.0f / (1.0f + expf(-acc));
    }
    __syncthreads();
    if (t < NH) {
        float mx = -1e30f;
        for (int mm = 0; mm < NM; mm++) mx = fmaxf(mx, pi_raw[t * NM + mm]);
        float s = 0.f, e[NM];
        for (int mm = 0; mm < NM; mm++) { e[mm] = expf(pi_raw[t * NM + mm] - mx); s += e[mm]; }
        for (int mm = 0; mm < NM; mm++) pi_s[t][mm] = e[mm] / s;
    }
    __syncthreads();

    // ======== gate[h][n] = log(sum_m pi[h,m]*ew_raw[n,m] + EPS)  (last reader of ew_s) ========
    {
        int h = wave, n = lane;
        float wv = 0.f;
        for (int mm = 0; mm < NM; mm++) wv += pi_s[h][mm] * ew_s[n * NM + mm];
        gate_s[h][n] = logf(wv + EPSC);
    }
    __syncthreads();

    // ======== attention + FF layers ========
    const float inv_tau_scale = 0.25f / expf(P.log_tau[wave]);  // scale=1/sqrt(16)
    for (int l = 0; l < NLAYER; l++) {
        const float* Wq  = P.L_Wq  + l * ND * ND;
        const float* Wk  = P.L_Wk  + l * ND * ND;
        const float* Wvv = P.L_Wv  + l * ND * ND;
        const float* Wo  = P.L_Wo  + l * ND * ND;
        const float* ln1g = P.L_ln1g + l * ND;
        const float* ln1b = P.L_ln1b + l * ND;
        const float* ln2g = P.L_ln2g + l * ND;
        const float* ln2b = P.L_ln2b + l * ND;
        const float* Wf1 = P.L_Wf1 + l * ND * NFF;
        const float* bf1 = P.L_bf1 + l * NFF;
        const float* Wf2 = P.L_Wf2 + l * NFF * ND;
        const float* bf2 = P.L_bf2 + l * ND;

        if (t < ND) {
            float acc = 0.f;
            for (int k = 0; k < ND; k++) acc += xcur[k] * Wq[k * ND + t];
            qv[t] = acc;
        }
        // K/V projections from h_nei_shared (no bias in reference)
        {
            const int d = lane;
            const int n0 = wave * 16;
            float acck[16], accv[16];
#pragma unroll
            for (int i = 0; i < 16; i++) { acck[i] = 0.f; accv[i] = 0.f; }
            for (int kt = 0; kt < ND; kt += 4) {
                float wk[4], wv[4];
#pragma unroll
                for (int j = 0; j < 4; j++) {
                    wk[j] = Wk[(kt + j) * ND + d];
                    wv[j] = Wvv[(kt + j) * ND + d];
                }
#pragma unroll
                for (int i = 0; i < 16; i++) {
                    const float4 hr = *(const float4*)&hns[n0 + i][kt];
                    acck[i] += hr.x * wk[0] + hr.y * wk[1] + hr.z * wk[2] + hr.w * wk[3];
                    accv[i] += hr.x * wv[0] + hr.y * wv[1] + hr.z * wv[2] + hr.w * wv[3];
                }
            }
            // K row-major [n][d], 16B-chunk swizzle: chunk c of row n lives at c^(n&7)
            const int cK = d >> 3;
            const int sK = d & 7;
#pragma unroll
            for (int i = 0; i < 16; i++) {
                int n = n0 + i;
                ushort_t* kp = (ushort_t*)(kbuf + n * 128 + (((cK ^ (n & 7)) << 4)));
                kp[sK] = f2bf(acck[i]);
            }
            // V transposed [d][n], packed 8xbf16 stores, chunk swizzle: chunk c of row d at c^(d&7)
            union { ushort_t u[8]; uint4 q; } pk0, pk1;
#pragma unroll
            for (int j = 0; j < 8; j++) { pk0.u[j] = f2bf(accv[j]); pk1.u[j] = f2bf(accv[j + 8]); }
            char* rowv = vbuf + d * 128;
            *(uint4*)(rowv + (((2 * wave)     ^ (d & 7)) << 4)) = pk0.q;
            *(uint4*)(rowv + (((2 * wave + 1) ^ (d & 7)) << 4)) = pk1.q;
        }
        __syncthreads();
        // scores + softmax over n (one head per wave) — K read as 2x b128
        {
            const int h = wave, n = lane;
            const float4 q0 = *(const float4*)&qv[h * 16 + 0];
            const float4 q1 = *(const float4*)&qv[h * 16 + 4];
            const float4 q2 = *(const float4*)&qv[h * 16 + 8];
            const float4 q3 = *(const float4*)&qv[h * 16 + 12];
            const char* rowk = kbuf + n * 128;
            uint4 ka = *(const uint4*)(rowk + (((2 * h)     ^ (n & 7)) << 4));
            uint4 kb = *(const uint4*)(rowk + (((2 * h + 1) ^ (n & 7)) << 4));
            const ushort_t* ua = (const ushort_t*)&ka;
            const ushort_t* ub = (const ushort_t*)&kb;
            float s = q0.x * bf2f(ua[0]) + q0.y * bf2f(ua[1]) + q0.z * bf2f(ua[2]) + q0.w * bf2f(ua[3])
                    + q1.x * bf2f(ua[4]) + q1.y * bf2f(ua[5]) + q1.z * bf2f(ua[6]) + q1.w * bf2f(ua[7])
                    + q2.x * bf2f(ub[0]) + q2.y * bf2f(ub[1]) + q2.z * bf2f(ub[2]) + q2.w * bf2f(ub[3])
                    + q3.x * bf2f(ub[4]) + q3.y * bf2f(ub[5]) + q3.z * bf2f(ub[6]) + q3.w * bf2f(ub[7]);
            s = s * inv_tau_scale + gate_s[h][n];
            float mx = wmax64(s);
            float e = expf(s - mx);
            float se = wsum64(e);
            attn_f[h * NN + n] = e / se;
        }
        __syncthreads();
        // PV: lane t owns output dim t; V^T row read as 8x b128
        if (t < ND) {
            const int h = t >> 4;
            const float* attn_h = attn_f + h * NN;
            const char* rowv = vbuf + t * 128;
            float acc = 0.f;
#pragma unroll
            for (int c = 0; c < 8; c++) {
                uint4 vq = *(const uint4*)(rowv + (((c ^ (t & 7))) << 4));
                const ushort_t* u = (const ushort_t*)&vq;
                float4 a0 = *(const float4*)&attn_h[c * 8];
                float4 a1 = *(const float4*)&attn_h[c * 8 + 4];
                acc += a0.x * bf2f(u[0]) + a0.y * bf2f(u[1]) + a0.z * bf2f(u[2]) + a0.w * bf2f(u[3])
                     + a1.x * bf2f(u[4]) + a1.y * bf2f(u[5]) + a1.z * bf2f(u[6]) + a1.w * bf2f(u[7]);
            }
            ctx_s[t] = acc;
        }
        __syncthreads();
        if (t < ND) {
            float acc = 0.f;
            for (int c = 0; c < ND; c++) acc += ctx_s[c] * Wo[c * ND + t];
            float xv = xcur[t] + acc;
            float mean = wsum64(xv) * (1.0f / 64.0f);
            float dv = xv - mean;
            float var = wsum64(dv * dv) * (1.0f / 64.0f);
            xcur[t] = dv * rsqrtf(var + 1e-5f) * ln1g[t] + ln1b[t];
        }
        __syncthreads();
        if (t < NFF) {
            float acc = bf1[t];
            for (int d = 0; d < ND; d++) acc += xcur[d] * Wf1[d * NFF + t];
            ffs[t] = gelu_f(acc);
        }
        __syncthreads();
        if (t < ND) {
            float acc = bf2[t];
            for (int j = 0; j < NFF; j++) acc += ffs[j] * Wf2[j * ND + t];
            float xv = xcur[t] + acc;
            float mean = wsum64(xv) * (1.0f / 64.0f);
            float dv = xv - mean;
            float var = wsum64(dv * dv) * (1.0f / 64.0f);
            xcur[t] = dv * rsqrtf(var + 1e-5f) * ln2g[t] + ln2b[t];
        }
        __syncthreads();
    }

    // ======== blended + final head ========
    if (t < ND) {
        float acc = 0.f;
#pragma unroll
        for (int h = 0; h < NH; h++) {
            float iso = 0.f;
#pragma unroll
            for (int mm = 0; mm < NM; mm++) iso += pi_s[h][mm] * pvc[mm][t];
            acc += (1.0f - beta_s[h]) * iso + beta_s[h] * xcur[t];
        }
        float bl = acc * 0.25f;
        float mean = wsum64(bl) * (1.0f / 64.0f);
        float dv = bl - mean;
        float var = wsum64(dv * dv) * (1.0f / 64.0f);
        sAe[t] = dv * rsqrtf(var + 1e-5f) * P.p_lng[t] + P.p_lnb[t];
    }
    __syncthreads();
    if (t < 32) {
        float acc = P.p_b1[t];
        for (int d = 0; d < ND; d++) acc += sAe[d] * P.p_W1[d * 32 + t];
        sBe[t] = gelu_f(acc);
    }
    __syncthreads();
    if (t < NOUT) {
        float acc = P.p_b2[t];
        for (int j = 0; j < 32; j++) acc += sBe[j] * P.p_W2[j * NOUT + t];
        P.out[(size_t)b * NOUT + t] = acc;
    }
}

extern "C" void kernel_launch(void* const* d_in, const int* in_sizes, int n_in,
                              void* d_out, int out_size, void* d_ws, size_t ws_size,
                              hipStream_t stream)
{
    (void)in_sizes; (void)n_in; (void)d_ws; (void)ws_size; (void)out_size;
    GParams P;
    P.x_anc   = (const float*)d_in[0];
    P.g_anc   = (const float*)d_in[1];
    P.x_nei   = (const float*)d_in[2];
    P.ew_anc  = (const float*)d_in[3];
    P.W_anc   = (const float*)d_in[4];
    P.b_anc   = (const float*)d_in[5];
    P.Wv_emb  = (const float*)d_in[6];
    P.bv_emb  = (const float*)d_in[7];
    P.Wv_val  = (const float*)d_in[8];
    P.bv_val  = (const float*)d_in[9];
    P.r_Win   = (const float*)d_in[10];
    P.r_bin   = (const float*)d_in[11];
    P.r_lng   = (const float*)d_in[12];
    P.r_lnb   = (const float*)d_in[13];
    P.r_W1    = (const float*)d_in[14];
    P.r_b1    = (const float*)d_in[15];
    P.r_W2    = (const float*)d_in[16];
    P.r_b2    = (const float*)d_in[17];
    P.r_Wview = (const float*)d_in[18];
    P.r_bview = (const float*)d_in[19];
    P.r_Wmode = (const float*)d_in[20];
    P.r_bmode = (const float*)d_in[21];
    P.log_tau = (const float*)d_in[22];
    P.L_Wq    = (const float*)d_in[23];
    P.L_Wk    = (const float*)d_in[24];
    P.L_Wv    = (const float*)d_in[25];
    P.L_Wo    = (const float*)d_in[26];
    P.L_ln1g  = (const float*)d_in[27];
    P.L_ln1b  = (const float*)d_in[28];
    P.L_ln2g  = (const float*)d_in[29];
    P.L_ln2b  = (const float*)d_in[30];
    P.L_Wf1   = (const float*)d_in[31];
    P.L_bf1   = (const float*)d_in[32];
    P.L_Wf2   = (const float*)d_in[33];
    P.L_bf2   = (const float*)d_in[34];
    P.p_lng   = (const float*)d_in[35];
    P.p_lnb   = (const float*)d_in[36];
    P.p_W1    = (const float*)d_in[37];
    P.p_b1    = (const float*)d_in[38];
    P.p_W2    = (const float*)d_in[39];
    P.p_b2    = (const float*)d_in[40];
    P.out     = (float*)d_out;
    hipLaunchKernelGGL(gora_fused, dim3(NB), dim3(256), 0, stream, P);
}

// Round 3
// 627.058 us; speedup vs baseline: 1.3383x; 1.2510x over previous
//
#include <hip/hip_runtime.h>
#include <hip/hip_bf16.h>
#include <math.h>

#define NB 4096
#define NN 64
#define NM 4
#define NF 128
#define NOBS 64
#define ND 64
#define NH 4
#define NLAYER 2
#define NFF 128
#define NHID 64
#define NOUT 8
#define EPSC 1e-6f

struct GParams {
    const float* x_anc; const float* g_anc; const float* x_nei; const float* ew_anc;
    const float* W_anc; const float* b_anc;
    const float* Wv_emb; const float* bv_emb; const float* Wv_val; const float* bv_val;
    const float* r_Win; const float* r_bin; const float* r_lng; const float* r_lnb;
    const float* r_W1; const float* r_b1; const float* r_W2; const float* r_b2;
    const float* r_Wview; const float* r_bview; const float* r_Wmode; const float* r_bmode;
    const float* log_tau;
    const float* L_Wq; const float* L_Wk; const float* L_Wv; const float* L_Wo;
    const float* L_ln1g; const float* L_ln1b; const float* L_ln2g; const float* L_ln2b;
    const float* L_Wf1; const float* L_bf1; const float* L_Wf2; const float* L_bf2;
    const float* p_lng; const float* p_lnb; const float* p_W1; const float* p_b1;
    const float* p_W2; const float* p_b2;
    float* out;
};

__device__ __forceinline__ float gelu_f(float x) {
    return 0.5f * x * (1.0f + erff(x * 0.7071067811865476f));
}
__device__ __forceinline__ float wsum64(float v) {
#pragma unroll
    for (int off = 32; off > 0; off >>= 1) v += __shfl_xor(v, off, 64);
    return v;
}
__device__ __forceinline__ float wmax64(float v) {
#pragma unroll
    for (int off = 32; off > 0; off >>= 1) v = fmaxf(v, __shfl_xor(v, off, 64));
    return v;
}

// launch_bounds notes (measured this session):
//  (256,4): allocator clamps to 64 VGPR -> hacc/acck/accv spill, WRITE_SIZE 128KB->45MB, 662us.
//  (256,2): VGPR=88 no spill, but only 2 blocks/CU resident (22.9% occ) even when LDS fits 4.
//  (256,3): VGPR budget ~170 (no clamp below natural 88) AND 3 blocks/CU residency target;
//           LDS ~43.5KB caps at 3 blocks/CU anyway.
__global__ __launch_bounds__(256, 3)
void gora_fused(GParams P)
{
    const int b = blockIdx.x;
    const int t = threadIdx.x;
    const int lane = t & 63;
    const int wave = t >> 6;

    // ---- LDS ~43.5 KB -> 3 blocks/CU ----
    // u1buf: phase 1 holds x_nei[b] in bf16 (xsf); after the h_nei GEMM it is
    // overwritten with h_nei_shared fp32 (hns). Saves 16 KB vs separate arrays.
    __shared__ alignas(16) char u1buf[NN * NF * 2];  // 16 KB
    __shared__ float hv[NM][ND];
    __shared__ __hip_bfloat16 kb16[NN][ND + 2];      // 8.25KB K (padded rows: 66 elems)
    __shared__ __hip_bfloat16 vb16[NN][ND + 2];      // 8.25KB V
    __shared__ float ew_s[NN * NM];                  // raw masked ew  [n*4+m]
    __shared__ float winv[NM], wssum[NM];
    __shared__ float xa[NF];
    __shared__ float ga[NOBS];
    __shared__ float xw[NM][NF];
    __shared__ float pvc[NM][ND];
    __shared__ float hfin[NHID];
    __shared__ float pi_raw[NH * NM];
    __shared__ float pi_s[NH][NM];
    __shared__ float beta_s[NH];
    __shared__ float gate_s[NH][NN];
    __shared__ float xcur[ND];
    __shared__ float qv[ND];
    __shared__ float attn_s[NH][NN];
    __shared__ float ctx_s[ND];
    __shared__ float ffs[NFF];
    __shared__ float sA[ND];
    __shared__ float sB[ND];

    __hip_bfloat16* xsf = (__hip_bfloat16*)u1buf;    // phase 1 view
    float (*hns)[ND]    = (float (*)[ND])u1buf;      // phase 2+ view (overlays xsf)

    // ================= loads =================
    {
        float e = P.ew_anc[(size_t)b * NN * NM + t];   // 256 = N*M exactly
        ew_s[t] = (e > 0.0f) ? e : 0.0f;               // ew * (ew>0)
    }
    if (t < NF) xa[t] = P.x_anc[(size_t)b * NF + t];
    else if (t < NF + NOBS) ga[t - NF] = P.g_anc[(size_t)b * NOBS + (t - NF)];
    {
        const float4* xn4 = (const float4*)(P.x_nei + (size_t)b * NN * NF);
#pragma unroll
        for (int i = 0; i < 8; i++) {
            int i4 = t + i * 256;                      // 2048 float4 total
            float4 v4 = xn4[i4];
            __hip_bfloat162 p0, p1;
            p0.x = __float2bfloat16(v4.x); p0.y = __float2bfloat16(v4.y);
            p1.x = __float2bfloat16(v4.z); p1.y = __float2bfloat16(v4.w);
            __hip_bfloat162* dst = (__hip_bfloat162*)&xsf[i4 * 4];
            dst[0] = p0; dst[1] = p1;
        }
    }
    __syncthreads();

    // ======== view-weight norms (t<4) + h_anc (t in [64,128)) ========
    if (t < NM) {
        float s = 0.0f;
        for (int n = 0; n < NN; n++) s += ew_s[n * NM + t];
        float c = fmaxf(s, EPSC);
        winv[t]  = 1.0f / c;
        wssum[t] = s / c;                 // sum of normalized weights (0 or 1-ish)
    }
    if (t >= 64 && t < 128) {
        int d = t - 64;
        float acc = P.b_anc[d];
        for (int f = 0; f < NF; f++) acc += xa[f] * P.W_anc[f * ND + d];
        xcur[d] = acc;                    // x = h_anc
    }
    __syncthreads();

    // ======== xw[m][f] = sum_n w[m,n] * x_nei[n,f] ========
    {
        int f = t & (NF - 1);
        int m0 = t >> 7;                  // wave-uniform (0 or 1)
        float a0 = 0.f, a1 = 0.f;
        for (int n = 0; n < NN; n++) {
            float xv = __bfloat162float(xsf[n * NF + f]);
            a0 += ew_s[n * NM + m0] * xv;
            a1 += ew_s[n * NM + m0 + 2] * xv;
        }
        xw[m0][f]     = a0 * winv[m0];
        xw[m0 + 2][f] = a1 * winv[m0 + 2];
    }

    // ======== h_nei_shared = x_nei @ Wv_emb[0] + bv_emb[0]  (64x128 @ 128x64) ========
    // Accumulate in registers; write to hns AFTER the barrier (hns overlays xsf).
    float hacc[16];
    {
        const int d = lane;
        const int n0 = wave * 16;
        float bias = P.bv_emb[d];         // m = 0
#pragma unroll
        for (int i = 0; i < 16; i++) hacc[i] = bias;
        const float* W0 = P.Wv_emb;       // m = 0 block
        for (int ft = 0; ft < NF; ft += 8) {
            float w0r[8];
#pragma unroll
            for (int j = 0; j < 8; j++) w0r[j] = W0[(ft + j) * ND + d];
#pragma unroll
            for (int i = 0; i < 16; i++) {
                const float4 xr = *(const float4*)&xsf[(n0 + i) * NF + ft]; // 8 bf16
                const __hip_bfloat162* xp = (const __hip_bfloat162*)&xr;
#pragma unroll
                for (int j = 0; j < 4; j++) {
                    hacc[i] += __bfloat162float(xp[j].x) * w0r[2 * j];
                    hacc[i] += __bfloat162float(xp[j].y) * w0r[2 * j + 1];
                }
            }
        }
    }
    __syncthreads();   // all xsf readers (xw phase + hacc) done; xw visible below
    {
        const int d = lane;
        const int n0 = wave * 16;
#pragma unroll
        for (int i = 0; i < 16; i++) hns[n0 + i][d] = hacc[i];   // overlays xsf
    }

    // ======== per_view_ctx: hv = xw@Wv_emb[m] + s*bv_emb ; pvc = hv@Wv_val[m] + s*bv_val ========
    {
        int m = wave, d = lane;
        float acc = wssum[m] * P.bv_emb[m * ND + d];
        const float* We = P.Wv_emb + (size_t)m * NF * ND;
        for (int f = 0; f < NF; f++) acc += xw[m][f] * We[f * ND + d];
        hv[m][d] = acc;
    }
    __syncthreads();
    {
        int m = wave, d = lane;
        float acc = wssum[m] * P.bv_val[m * ND + d];
        const float* Wv = P.Wv_val + (size_t)m * ND * ND;
        for (int k = 0; k < ND; k++) acc += hv[m][k] * Wv[k * ND + d];
        pvc[m][d] = acc;
    }
    __syncthreads();

    // ======== ctx_vec + r-MLP ========
    if (t < ND) sA[t] = 0.25f * (pvc[0][t] + pvc[1][t] + pvc[2][t] + pvc[3][t]);
    __syncthreads();
    if (t < NHID) {
        float acc = P.r_bin[t];
        for (int f = 0; f < NOBS; f++) acc += ga[f] * P.r_Win[f * NHID + t];
        for (int f = 0; f < ND;   f++) acc += sA[f] * P.r_Win[(NOBS + f) * NHID + t];
        float mean = wsum64(acc) * (1.0f / 64.0f);
        float dv = acc - mean;
        float var = wsum64(dv * dv) * (1.0f / 64.0f);
        float xln = dv * rsqrtf(var + 1e-5f) * P.r_lng[t] + P.r_lnb[t];
        sB[t] = gelu_f(xln);
    }
    __syncthreads();
    if (t < NHID) {
        float acc = P.r_b1[t];
        for (int k = 0; k < NHID; k++) acc += sB[k] * P.r_W1[k * NHID + t];
        sA[t] = gelu_f(acc);
    }
    __syncthreads();
    if (t < NHID) {
        float acc = P.r_b2[t];
        for (int k = 0; k < NHID; k++) acc += sA[k] * P.r_W2[k * NHID + t];
        hfin[t] = gelu_f(acc);
    }
    __syncthreads();

    // ======== pi (softmax over views), beta ========
    if (t < NH * NM) {
        int h = t >> 2, mm = t & 3;
        float acc = P.r_bview[h * NM + mm];
        for (int k = 0; k < NHID; k++) acc += hfin[k] * P.r_Wview[(h * NHID + k) * NM + mm];
        pi_raw[t] = acc;
    }
    if (t >= 64 && t < 64 + NH) {
        int h = t - 64;
        float acc = P.r_bmode[h];
        for (int k = 0; k < NHID; k++) acc += hfin[k] * P.r_Wmode[h * NHID + k];
        beta_s[h] = 1.0f / (1.0f + expf(-acc));
    }
    __syncthreads();
    if (t < NH) {
        float mx = -1e30f;
        for (int mm = 0; mm < NM; mm++) mx = fmaxf(mx, pi_raw[t * NM + mm]);
        float s = 0.f, e[NM];
        for (int mm = 0; mm < NM; mm++) { e[mm] = expf(pi_raw[t * NM + mm] - mx); s += e[mm]; }
        for (int mm = 0; mm < NM; mm++) pi_s[t][mm] = e[mm] / s;
    }
    __syncthreads();

    // ======== gate[h][n] = log(sum_m pi[h,m]*ew_raw[n,m] + EPS) ========
    {
        int h = wave, n = lane;
        float wv = 0.f;
        for (int mm = 0; mm < NM; mm++) wv += pi_s[h][mm] * ew_s[n * NM + mm];
        gate_s[h][n] = logf(wv + EPSC);
    }
    __syncthreads();

    // ======== attention + FF layers ========
    const float inv_tau_scale = 0.25f / expf(P.log_tau[wave]);  // scale=1/sqrt(16)
    for (int l = 0; l < NLAYER; l++) {
        const float* Wq  = P.L_Wq  + l * ND * ND;
        const float* Wk  = P.L_Wk  + l * ND * ND;
        const float* Wvv = P.L_Wv  + l * ND * ND;
        const float* Wo  = P.L_Wo  + l * ND * ND;
        const float* ln1g = P.L_ln1g + l * ND;
        const float* ln1b = P.L_ln1b + l * ND;
        const float* ln2g = P.L_ln2g + l * ND;
        const float* ln2b = P.L_ln2b + l * ND;
        const float* Wf1 = P.L_Wf1 + l * ND * NFF;
        const float* bf1 = P.L_bf1 + l * NFF;
        const float* Wf2 = P.L_Wf2 + l * NFF * ND;
        const float* bf2 = P.L_bf2 + l * ND;

        if (t < ND) {
            float acc = 0.f;
            for (int k = 0; k < ND; k++) acc += xcur[k] * Wq[k * ND + t];
            qv[t] = acc;
        }
        // K/V projections from h_nei_shared (no bias in reference)
        {
            const int d = lane;
            const int n0 = wave * 16;
            float acck[16], accv[16];
#pragma unroll
            for (int i = 0; i < 16; i++) { acck[i] = 0.f; accv[i] = 0.f; }
            for (int kt = 0; kt < ND; kt += 4) {
                float wk[4], wv[4];
#pragma unroll
                for (int j = 0; j < 4; j++) {
                    wk[j] = Wk[(kt + j) * ND + d];
                    wv[j] = Wvv[(kt + j) * ND + d];
                }
#pragma unroll
                for (int i = 0; i < 16; i++) {
                    const float4 hr = *(const float4*)&hns[n0 + i][kt];
                    acck[i] += hr.x * wk[0] + hr.y * wk[1] + hr.z * wk[2] + hr.w * wk[3];
                    accv[i] += hr.x * wv[0] + hr.y * wv[1] + hr.z * wv[2] + hr.w * wv[3];
                }
            }
#pragma unroll
            for (int i = 0; i < 16; i++) {
                kb16[n0 + i][d] = __float2bfloat16(acck[i]);
                vb16[n0 + i][d] = __float2bfloat16(accv[i]);
            }
        }
        __syncthreads();
        // scores + softmax over n (one head per wave)
        {
            int h = wave, n = lane;
            float s = 0.f;
#pragma unroll
            for (int j = 0; j < 16; j++)
                s += qv[h * 16 + j] * __bfloat162float(kb16[n][h * 16 + j]);
            s = s * inv_tau_scale + gate_s[h][n];
            float mx = wmax64(s);
            float e = expf(s - mx);
            float se = wsum64(e);
            attn_s[h][n] = e / se;
        }
        __syncthreads();
        if (t < ND) {
            int h = t >> 4;
            float acc = 0.f;
            for (int n = 0; n < NN; n++) acc += attn_s[h][n] * __bfloat162float(vb16[n][t]);
            ctx_s[t] = acc;
        }
        __syncthreads();
        if (t < ND) {
            float acc = 0.f;
            for (int c = 0; c < ND; c++) acc += ctx_s[c] * Wo[c * ND + t];
            float xv = xcur[t] + acc;
            float mean = wsum64(xv) * (1.0f / 64.0f);
            float dv = xv - mean;
            float var = wsum64(dv * dv) * (1.0f / 64.0f);
            xcur[t] = dv * rsqrtf(var + 1e-5f) * ln1g[t] + ln1b[t];
        }
        __syncthreads();
        if (t < NFF) {
            float acc = bf1[t];
            for (int d = 0; d < ND; d++) acc += xcur[d] * Wf1[d * NFF + t];
            ffs[t] = gelu_f(acc);
        }
        __syncthreads();
        if (t < ND) {
            float acc = bf2[t];
            for (int j = 0; j < NFF; j++) acc += ffs[j] * Wf2[j * ND + t];
            float xv = xcur[t] + acc;
            float mean = wsum64(xv) * (1.0f / 64.0f);
            float dv = xv - mean;
            float var = wsum64(dv * dv) * (1.0f / 64.0f);
            xcur[t] = dv * rsqrtf(var + 1e-5f) * ln2g[t] + ln2b[t];
        }
        __syncthreads();
    }

    // ======== blended + final head ========
    if (t < ND) {
        float acc = 0.f;
#pragma unroll
        for (int h = 0; h < NH; h++) {
            float iso = 0.f;
#pragma unroll
            for (int mm = 0; mm < NM; mm++) iso += pi_s[h][mm] * pvc[mm][t];
            acc += (1.0f - beta_s[h]) * iso + beta_s[h] * xcur[t];
        }
        float bl = acc * 0.25f;
        float mean = wsum64(bl) * (1.0f / 64.0f);
        float dv = bl - mean;
        float var = wsum64(dv * dv) * (1.0f / 64.0f);
        sA[t] = dv * rsqrtf(var + 1e-5f) * P.p_lng[t] + P.p_lnb[t];
    }
    __syncthreads();
    if (t < 32) {
        float acc = P.p_b1[t];
        for (int d = 0; d < ND; d++) acc += sA[d] * P.p_W1[d * 32 + t];
        sB[t] = gelu_f(acc);
    }
    __syncthreads();
    if (t < NOUT) {
        float acc = P.p_b2[t];
        for (int j = 0; j < 32; j++) acc += sB[j] * P.p_W2[j * NOUT + t];
        P.out[(size_t)b * NOUT + t] = acc;
    }
}

extern "C" void kernel_launch(void* const* d_in, const int* in_sizes, int n_in,
                              void* d_out, int out_size, void* d_ws, size_t ws_size,
                              hipStream_t stream)
{
    (void)in_sizes; (void)n_in; (void)d_ws; (void)ws_size; (void)out_size;
    GParams P;
    P.x_anc   = (const float*)d_in[0];
    P.g_anc   = (const float*)d_in[1];
    P.x_nei   = (const float*)d_in[2];
    P.ew_anc  = (const float*)d_in[3];
    P.W_anc   = (const float*)d_in[4];
    P.b_anc   = (const float*)d_in[5];
    P.Wv_emb  = (const float*)d_in[6];
    P.bv_emb  = (const float*)d_in[7];
    P.Wv_val  = (const float*)d_in[8];
    P.bv_val  = (const float*)d_in[9];
    P.r_Win   = (const float*)d_in[10];
    P.r_bin   = (const float*)d_in[11];
    P.r_lng   = (const float*)d_in[12];
    P.r_lnb   = (const float*)d_in[13];
    P.r_W1    = (const float*)d_in[14];
    P.r_b1    = (const float*)d_in[15];
    P.r_W2    = (const float*)d_in[16];
    P.r_b2    = (const float*)d_in[17];
    P.r_Wview = (const float*)d_in[18];
    P.r_bview = (const float*)d_in[19];
    P.r_Wmode = (const float*)d_in[20];
    P.r_bmode = (const float*)d_in[21];
    P.log_tau = (const float*)d_in[22];
    P.L_Wq    = (const float*)d_in[23];
    P.L_Wk    = (const float*)d_in[24];
    P.L_Wv    = (const float*)d_in[25];
    P.L_Wo    = (const float*)d_in[26];
    P.L_ln1g  = (const float*)d_in[27];
    P.L_ln1b  = (const float*)d_in[28];
    P.L_ln2g  = (const float*)d_in[29];
    P.L_ln2b  = (const float*)d_in[30];
    P.L_Wf1   = (const float*)d_in[31];
    P.L_bf1   = (const float*)d_in[32];
    P.L_Wf2   = (const float*)d_in[33];
    P.L_bf2   = (const float*)d_in[34];
    P.p_lng   = (const float*)d_in[35];
    P.p_lnb   = (const float*)d_in[36];
    P.p_W1    = (const float*)d_in[37];
    P.p_b1    = (const float*)d_in[38];
    P.p_W2    = (const float*)d_in[39];
    P.p_b2    = (const float*)d_in[40];
    P.out     = (float*)d_out;
    hipLaunchKernelGGL(gora_fused, dim3(NB), dim3(256), 0, stream, P);
}

// Round 4
// 447.071 us; speedup vs baseline: 1.8770x; 1.4026x over previous
//
#include <hip/hip_runtime.h>
#include <hip/hip_bf16.h>
#include <math.h>

#define NB 4096
#define NN 64
#define NM 4
#define NF 128
#define NOBS 64
#define ND 64
#define NH 4
#define NLAYER 2
#define NFF 128
#define NHID 64
#define NOUT 8
#define EPSC 1e-6f

typedef unsigned short ushort_t;
typedef __attribute__((ext_vector_type(8))) short short8v;   // 8 bf16 (4 VGPR) MFMA A/B frag
typedef __attribute__((ext_vector_type(4))) float f32x4;     // MFMA C/D frag

#define MFMA16(a, b, c) __builtin_amdgcn_mfma_f32_16x16x32_bf16((a), (b), (c), 0, 0, 0)

struct GParams {
    const float* x_anc; const float* g_anc; const float* x_nei; const float* ew_anc;
    const float* W_anc; const float* b_anc;
    const float* Wv_emb; const float* bv_emb; const float* Wv_val; const float* bv_val;
    const float* r_Win; const float* r_bin; const float* r_lng; const float* r_lnb;
    const float* r_W1; const float* r_b1; const float* r_W2; const float* r_b2;
    const float* r_Wview; const float* r_bview; const float* r_Wmode; const float* r_bmode;
    const float* log_tau;
    const float* L_Wq; const float* L_Wk; const float* L_Wv; const float* L_Wo;
    const float* L_ln1g; const float* L_ln1b; const float* L_ln2g; const float* L_ln2b;
    const float* L_Wf1; const float* L_bf1; const float* L_Wf2; const float* L_bf2;
    const float* p_lng; const float* p_lnb; const float* p_W1; const float* p_b1;
    const float* p_W2; const float* p_b2;
    const uint4* wsf;     // prepped split-bf16 weight fragments (see prep_w)
    float* out;
};

__device__ __forceinline__ float gelu_f(float x) {
    return 0.5f * x * (1.0f + erff(x * 0.7071067811865476f));
}
__device__ __forceinline__ float wsum64(float v) {
#pragma unroll
    for (int off = 32; off > 0; off >>= 1) v += __shfl_xor(v, off, 64);
    return v;
}
__device__ __forceinline__ float wmax64(float v) {
#pragma unroll
    for (int off = 32; off > 0; off >>= 1) v = fmaxf(v, __shfl_xor(v, off, 64));
    return v;
}
__device__ __forceinline__ float bf2f(ushort_t u) {
    union { unsigned int i; float f; } c; c.i = ((unsigned int)u) << 16; return c.f;
}
__device__ __forceinline__ ushort_t f2bf(float f) {
    __hip_bfloat16 h = __float2bfloat16(f);
    ushort_t u; __builtin_memcpy(&u, &h, 2); return u;
}
__device__ __forceinline__ short8v ld_frag(const uint4* p) {
    union { uint4 q; short8v v; } u; u.q = *p; return u.v;
}

// ---------------------------------------------------------------------------
// Weight prep: convert the block-shared GEMM weights into MFMA B-fragment
// layout, split into hi (bf16(w)) + lo (bf16(w - hi)) so that
// A*hi + A*lo ~= fp32-weight accuracy. Layout in ws (uint4 units):
//   [0,1024)     W0 (Wv_emb m=0, 128x64) hi   : 16 frags (ks<4,ct<4) * 64 lanes
//   [1024,2048)  W0 lo
//   [2048+1024*m ... ) for m = {K0,V0,K1,V1}: hi 512, lo 512 (8 frags, ks<2)
// frag(ks,ct,lane) element i: k = ks*32 + (lane>>4)*8 + i, d = ct*16 + (lane&15)
// ---------------------------------------------------------------------------
__global__ void prep_w(const float* Wv_emb, const float* L_Wk, const float* L_Wv, uint4* ws)
{
    int task = blockIdx.x * 256 + threadIdx.x;    // 48 frags * 64 lanes = 3072
    if (task >= 3072) return;
    int lane = task & 63;
    int frag = task >> 6;                         // 0..47
    const float* src; int ks, ct; uint4 *dhi, *dlo;
    if (frag < 16) {                              // W0
        ks = frag >> 2; ct = frag & 3;
        src = Wv_emb;
        dhi = ws + (size_t)frag * 64 + lane;
        dlo = ws + 1024 + (size_t)frag * 64 + lane;
    } else {
        int g = frag - 16;                        // 0..31
        int matidx = g >> 3;                      // 0=K0 1=V0 2=K1 3=V1
        int fi = g & 7;
        ks = fi >> 2; ct = fi & 3;                // ks in {0,1}
        src = ((matidx & 1) ? L_Wv : L_Wk) + (size_t)(matidx >> 1) * (ND * ND);
        dhi = ws + 2048 + (size_t)matidx * 1024 + (size_t)fi * 64 + lane;
        dlo = dhi + 512;
    }
    union { ushort_t u[8]; uint4 q; } hi, lo;
#pragma unroll
    for (int i = 0; i < 8; i++) {
        int k = ks * 32 + (lane >> 4) * 8 + i;
        int d = ct * 16 + (lane & 15);
        float w = src[k * ND + d];
        ushort_t h = f2bf(w);
        hi.u[i] = h;
        lo.u[i] = f2bf(w - bf2f(h));
    }
    *dhi = hi.q;
    *dlo = lo.q;
}

// launch_bounds notes (measured this session):
//  (256,4): allocator clamps to 64 VGPR -> spills, WRITE_SIZE 128KB->45MB, 662us.
//  (256,2): VGPR=88 no spill, but only 2 blocks/CU resident (22.9% occ).
//  (256,3): best measured: VGPR=84, 3 blocks/CU, 466us (round 3).
__global__ __launch_bounds__(256, 3)
void gora_fused(GParams P)
{
    const int b = blockIdx.x;
    const int t = threadIdx.x;
    const int lane = t & 63;
    const int wave = t >> 6;

    // ---- LDS ~43.5 KB -> 3 blocks/CU ----
    // u1buf phase 1: x_nei[b] bf16 (xsf), 16B-chunk XOR swizzled (chunk ^= row&15);
    // phase 2+: h_nei_shared fp32 (hns), same swizzle. Swizzle makes the MFMA
    // A-fragment b128 reads (16 lanes, same col-range, different rows) conflict-free.
    __shared__ alignas(16) char u1buf[NN * NF * 2];  // 16 KB
    __shared__ float hv[NM][ND];
    __shared__ __hip_bfloat16 kb16[NN][ND + 2];      // 8.25KB K (padded rows: 66 elems)
    __shared__ __hip_bfloat16 vb16[NN][ND + 2];      // 8.25KB V
    __shared__ float ew_s[NN * NM];                  // raw masked ew  [n*4+m]
    __shared__ float winv[NM], wssum[NM];
    __shared__ float xa[NF];
    __shared__ float ga[NOBS];
    __shared__ float xw[NM][NF];
    __shared__ float pvc[NM][ND];
    __shared__ float hfin[NHID];
    __shared__ float pi_raw[NH * NM];
    __shared__ float pi_s[NH][NM];
    __shared__ float beta_s[NH];
    __shared__ float gate_s[NH][NN];
    __shared__ float xcur[ND];
    __shared__ float qv[ND];
    __shared__ float attn_s[NH][NN];
    __shared__ float ctx_s[ND];
    __shared__ float ffs[NFF];
    __shared__ float sA[ND];
    __shared__ float sB[ND];

    // ================= loads =================
    {
        float e = P.ew_anc[(size_t)b * NN * NM + t];   // 256 = N*M exactly
        ew_s[t] = (e > 0.0f) ? e : 0.0f;               // ew * (ew>0)
    }
    if (t < NF) xa[t] = P.x_anc[(size_t)b * NF + t];
    else if (t < NF + NOBS) ga[t - NF] = P.g_anc[(size_t)b * NOBS + (t - NF)];
    {
        // xsf swizzled store: elem (n,f) byte = n*256 + ((f>>3 ^ (n&15))<<4) + (f&7)*2
        const float4* xn4 = (const float4*)(P.x_nei + (size_t)b * NN * NF);
#pragma unroll
        for (int i = 0; i < 8; i++) {
            int i4 = t + i * 256;                      // 2048 float4 total
            float4 v4 = xn4[i4];
            __hip_bfloat162 p0, p1;
            p0.x = __float2bfloat16(v4.x); p0.y = __float2bfloat16(v4.y);
            p1.x = __float2bfloat16(v4.z); p1.y = __float2bfloat16(v4.w);
            int n = i4 >> 5;                           // 32 8B-groups per 256B row
            int c = (i4 >> 1) & 15;                    // 16B chunk in row
            char* dstb = u1buf + n * 256 + ((c ^ (n & 15)) << 4) + (i4 & 1) * 8;
            ((__hip_bfloat162*)dstb)[0] = p0;
            ((__hip_bfloat162*)dstb)[1] = p1;
        }
    }
    __syncthreads();

    // ======== view-weight norms (t<4) + h_anc (t in [64,128)) ========
    if (t < NM) {
        float s = 0.0f;
        for (int n = 0; n < NN; n++) s += ew_s[n * NM + t];
        float c = fmaxf(s, EPSC);
        winv[t]  = 1.0f / c;
        wssum[t] = s / c;                 // sum of normalized weights (0 or 1-ish)
    }
    if (t >= 64 && t < 128) {
        int d = t - 64;
        float acc = P.b_anc[d];
        for (int f = 0; f < NF; f++) acc += xa[f] * P.W_anc[f * ND + d];
        xcur[d] = acc;                    // x = h_anc
    }
    __syncthreads();

    // ======== xw[m][f] = sum_n w[m,n] * x_nei[n,f]  (swizzled xsf reads) ========
    {
        int f = t & (NF - 1);
        int m0 = t >> 7;                  // wave-uniform (0 or 1)
        const char* base = u1buf + ((((f >> 3)) << 4)) * 0;  // (kept simple below)
        float a0 = 0.f, a1 = 0.f;
        for (int n = 0; n < NN; n++) {
            const ushort_t* xp = (const ushort_t*)(u1buf + n * 256 + (((f >> 3) ^ (n & 15)) << 4) + (f & 7) * 2);
            float xv = bf2f(*xp);
            a0 += ew_s[n * NM + m0] * xv;
            a1 += ew_s[n * NM + m0 + 2] * xv;
        }
        xw[m0][f]     = a0 * winv[m0];
        xw[m0 + 2][f] = a1 * winv[m0 + 2];
    }

    // ======== h_nei A-fragments (read xsf BEFORE the overwrite barrier) ========
    // A[r=l&15][k=8*(l>>4)+e + 32*ks] -> one b128 per (ks): row = n0+(l&15)
    short8v afr[4];
    {
        const int row = wave * 16 + (lane & 15);
        const int sub = lane >> 4;
#pragma unroll
        for (int ks = 0; ks < 4; ks++) {
            int c = ks * 4 + sub;
            afr[ks] = *(const short8v*)(u1buf + row * 256 + ((c ^ (row & 15)) << 4));
        }
    }
    __syncthreads();   // all xsf readers (xw + afr) done; xw visible below

    // ======== h_nei = xsf @ W0 + bv_emb[0] via MFMA; D -> hns (overlays xsf) ========
    {
        const int n0 = wave * 16;
        const int colb = lane & 15;
        const int rsub = lane >> 4;
#pragma unroll
        for (int ct = 0; ct < 4; ct++) {
            float bias = P.bv_emb[ct * 16 + colb];
            f32x4 c = {bias, bias, bias, bias};
#pragma unroll
            for (int ks = 0; ks < 4; ks++) {
                short8v bhi = ld_frag(P.wsf + (size_t)(ks * 4 + ct) * 64 + lane);
                short8v blo = ld_frag(P.wsf + 1024 + (size_t)(ks * 4 + ct) * 64 + lane);
                c = MFMA16(afr[ks], bhi, c);
                c = MFMA16(afr[ks], blo, c);
            }
#pragma unroll
            for (int e = 0; e < 4; e++) {
                int n = n0 + rsub * 4 + e;
                int d = ct * 16 + colb;
                *(float*)(u1buf + n * 256 + ((((d >> 2) ^ (n & 15))) << 4) + (d & 3) * 4) = c[e];
            }
        }
    }

    // ======== per_view_ctx: hv = xw@Wv_emb[m] + s*bv_emb ; pvc = hv@Wv_val[m] + s*bv_val ========
    {
        int m = wave, d = lane;
        float acc = wssum[m] * P.bv_emb[m * ND + d];
        const float* We = P.Wv_emb + (size_t)m * NF * ND;
        for (int f = 0; f < NF; f++) acc += xw[m][f] * We[f * ND + d];
        hv[m][d] = acc;
    }
    __syncthreads();
    {
        int m = wave, d = lane;
        float acc = wssum[m] * P.bv_val[m * ND + d];
        const float* Wv = P.Wv_val + (size_t)m * ND * ND;
        for (int k = 0; k < ND; k++) acc += hv[m][k] * Wv[k * ND + d];
        pvc[m][d] = acc;
    }
    __syncthreads();

    // ======== ctx_vec + r-MLP ========
    if (t < ND) sA[t] = 0.25f * (pvc[0][t] + pvc[1][t] + pvc[2][t] + pvc[3][t]);
    __syncthreads();
    if (t < NHID) {
        float acc = P.r_bin[t];
        for (int f = 0; f < NOBS; f++) acc += ga[f] * P.r_Win[f * NHID + t];
        for (int f = 0; f < ND;   f++) acc += sA[f] * P.r_Win[(NOBS + f) * NHID + t];
        float mean = wsum64(acc) * (1.0f / 64.0f);
        float dv = acc - mean;
        float var = wsum64(dv * dv) * (1.0f / 64.0f);
        float xln = dv * rsqrtf(var + 1e-5f) * P.r_lng[t] + P.r_lnb[t];
        sB[t] = gelu_f(xln);
    }
    __syncthreads();
    if (t < NHID) {
        float acc = P.r_b1[t];
        for (int k = 0; k < NHID; k++) acc += sB[k] * P.r_W1[k * NHID + t];
        sA[t] = gelu_f(acc);
    }
    __syncthreads();
    if (t < NHID) {
        float acc = P.r_b2[t];
        for (int k = 0; k < NHID; k++) acc += sA[k] * P.r_W2[k * NHID + t];
        hfin[t] = gelu_f(acc);
    }
    __syncthreads();

    // ======== pi (softmax over views), beta ========
    if (t < NH * NM) {
        int h = t >> 2, mm = t & 3;
        float acc = P.r_bview[h * NM + mm];
        for (int k = 0; k < NHID; k++) acc += hfin[k] * P.r_Wview[(h * NHID + k) * NM + mm];
        pi_raw[t] = acc;
    }
    if (t >= 64 && t < 64 + NH) {
        int h = t - 64;
        float acc = P.r_bmode[h];
        for (int k = 0; k < NHID; k++) acc += hfin[k] * P.r_Wmode[h * NHID + k];
        beta_s[h] = 1.0f / (1.0f + expf(-acc));
    }
    __syncthreads();
    if (t < NH) {
        float mx = -1e30f;
        for (int mm = 0; mm < NM; mm++) mx = fmaxf(mx, pi_raw[t * NM + mm]);
        float s = 0.f, e[NM];
        for (int mm = 0; mm < NM; mm++) { e[mm] = expf(pi_raw[t * NM + mm] - mx); s += e[mm]; }
        for (int mm = 0; mm < NM; mm++) pi_s[t][mm] = e[mm] / s;
    }
    __syncthreads();

    // ======== gate[h][n] = log(sum_m pi[h,m]*ew_raw[n,m] + EPS) ========
    {
        int h = wave, n = lane;
        float wv = 0.f;
        for (int mm = 0; mm < NM; mm++) wv += pi_s[h][mm] * ew_s[n * NM + mm];
        gate_s[h][n] = logf(wv + EPSC);
    }
    __syncthreads();

    // ======== attention + FF layers ========
    const float inv_tau_scale = 0.25f / expf(P.log_tau[wave]);  // scale=1/sqrt(16)
    for (int l = 0; l < NLAYER; l++) {
        const float* Wq  = P.L_Wq  + l * ND * ND;
        const float* Wo  = P.L_Wo  + l * ND * ND;
        const float* ln1g = P.L_ln1g + l * ND;
        const float* ln1b = P.L_ln1b + l * ND;
        const float* ln2g = P.L_ln2g + l * ND;
        const float* ln2b = P.L_ln2b + l * ND;
        const float* Wf1 = P.L_Wf1 + l * ND * NFF;
        const float* bf1 = P.L_bf1 + l * NFF;
        const float* Wf2 = P.L_Wf2 + l * NFF * ND;
        const float* bf2 = P.L_bf2 + l * ND;

        if (t < ND) {
            float acc = 0.f;
            for (int k = 0; k < ND; k++) acc += xcur[k] * Wq[k * ND + t];
            qv[t] = acc;
        }
        // ---- K/V projections via MFMA: K = hns@Wk, V = hns@Wv (split A and B) ----
        {
            const int n0 = wave * 16;
            const int row = n0 + (lane & 15);
            const int rsub = lane >> 4;
            short8v ahi[2], alo[2];
#pragma unroll
            for (int ks = 0; ks < 2; ks++) {
                int c0 = ks * 8 + rsub * 2;
                f32x4 x0 = *(const f32x4*)(u1buf + row * 256 + ((c0 ^ (row & 15)) << 4));
                f32x4 x1 = *(const f32x4*)(u1buf + row * 256 + (((c0 + 1) ^ (row & 15)) << 4));
                union { ushort_t u[8]; short8v v; } uh, ul;
#pragma unroll
                for (int i = 0; i < 8; i++) {
                    float w = (i < 4) ? x0[i] : x1[i - 4];
                    ushort_t h = f2bf(w);
                    uh.u[i] = h;
                    ul.u[i] = f2bf(w - bf2f(h));
                }
                ahi[ks] = uh.v; alo[ks] = ul.v;
            }
            const uint4* bbase = P.wsf + 2048 + (size_t)(l * 2) * 1024;
#pragma unroll
            for (int mat = 0; mat < 2; mat++) {           // 0 = K, 1 = V
                const uint4* bb = bbase + (size_t)mat * 1024;
                __hip_bfloat16* dst = mat ? &vb16[0][0] : &kb16[0][0];
#pragma unroll
                for (int ct = 0; ct < 4; ct++) {
                    f32x4 c = {0.f, 0.f, 0.f, 0.f};
#pragma unroll
                    for (int ks = 0; ks < 2; ks++) {
                        short8v bhi = ld_frag(bb + (size_t)(ks * 4 + ct) * 64 + lane);
                        short8v blo = ld_frag(bb + 512 + (size_t)(ks * 4 + ct) * 64 + lane);
                        c = MFMA16(ahi[ks], bhi, c);
                        c = MFMA16(ahi[ks], blo, c);
                        c = MFMA16(alo[ks], bhi, c);
                    }
#pragma unroll
                    for (int e = 0; e < 4; e++) {
                        int n = n0 + rsub * 4 + e;
                        dst[n * (ND + 2) + ct * 16 + (lane & 15)] = __float2bfloat16(c[e]);
                    }
                }
            }
        }
        __syncthreads();
        // scores + softmax over n (one head per wave)
        {
            int h = wave, n = lane;
            float s = 0.f;
#pragma unroll
            for (int j = 0; j < 16; j++)
                s += qv[h * 16 + j] * __bfloat162float(kb16[n][h * 16 + j]);
            s = s * inv_tau_scale + gate_s[h][n];
            float mx = wmax64(s);
            float e = expf(s - mx);
            float se = wsum64(e);
            attn_s[h][n] = e / se;
        }
        __syncthreads();
        if (t < ND) {
            int h = t >> 4;
            float acc = 0.f;
            for (int n = 0; n < NN; n++) acc += attn_s[h][n] * __bfloat162float(vb16[n][t]);
            ctx_s[t] = acc;
        }
        __syncthreads();
        if (t < ND) {
            float acc = 0.f;
            for (int c = 0; c < ND; c++) acc += ctx_s[c] * Wo[c * ND + t];
            float xv = xcur[t] + acc;
            float mean = wsum64(xv) * (1.0f / 64.0f);
            float dv = xv - mean;
            float var = wsum64(dv * dv) * (1.0f / 64.0f);
            xcur[t] = dv * rsqrtf(var + 1e-5f) * ln1g[t] + ln1b[t];
        }
        __syncthreads();
        if (t < NFF) {
            float acc = bf1[t];
            for (int d = 0; d < ND; d++) acc += xcur[d] * Wf1[d * NFF + t];
            ffs[t] = gelu_f(acc);
        }
        __syncthreads();
        if (t < ND) {
            float acc = bf2[t];
            for (int j = 0; j < NFF; j++) acc += ffs[j] * Wf2[j * ND + t];
            float xv = xcur[t] + acc;
            float mean = wsum64(xv) * (1.0f / 64.0f);
            float dv = xv - mean;
            float var = wsum64(dv * dv) * (1.0f / 64.0f);
            xcur[t] = dv * rsqrtf(var + 1e-5f) * ln2g[t] + ln2b[t];
        }
        __syncthreads();
    }

    // ======== blended + final head ========
    if (t < ND) {
        float acc = 0.f;
#pragma unroll
        for (int h = 0; h < NH; h++) {
            float iso = 0.f;
#pragma unroll
            for (int mm = 0; mm < NM; mm++) iso += pi_s[h][mm] * pvc[mm][t];
            acc += (1.0f - beta_s[h]) * iso + beta_s[h] * xcur[t];
        }
        float bl = acc * 0.25f;
        float mean = wsum64(bl) * (1.0f / 64.0f);
        float dv = bl - mean;
        float var = wsum64(dv * dv) * (1.0f / 64.0f);
        sA[t] = dv * rsqrtf(var + 1e-5f) * P.p_lng[t] + P.p_lnb[t];
    }
    __syncthreads();
    if (t < 32) {
        float acc = P.p_b1[t];
        for (int d = 0; d < ND; d++) acc += sA[d] * P.p_W1[d * 32 + t];
        sB[t] = gelu_f(acc);
    }
    __syncthreads();
    if (t < NOUT) {
        float acc = P.p_b2[t];
        for (int j = 0; j < 32; j++) acc += sB[j] * P.p_W2[j * NOUT + t];
        P.out[(size_t)b * NOUT + t] = acc;
    }
}

extern "C" void kernel_launch(void* const* d_in, const int* in_sizes, int n_in,
                              void* d_out, int out_size, void* d_ws, size_t ws_size,
                              hipStream_t stream)
{
    (void)in_sizes; (void)n_in; (void)ws_size; (void)out_size;
    GParams P;
    P.x_anc   = (const float*)d_in[0];
    P.g_anc   = (const float*)d_in[1];
    P.x_nei   = (const float*)d_in[2];
    P.ew_anc  = (const float*)d_in[3];
    P.W_anc   = (const float*)d_in[4];
    P.b_anc   = (const float*)d_in[5];
    P.Wv_emb  = (const float*)d_in[6];
    P.bv_emb  = (const float*)d_in[7];
    P.Wv_val  = (const float*)d_in[8];
    P.bv_val  = (const float*)d_in[9];
    P.r_Win   = (const float*)d_in[10];
    P.r_bin   = (const float*)d_in[11];
    P.r_lng   = (const float*)d_in[12];
    P.r_lnb   = (const float*)d_in[13];
    P.r_W1    = (const float*)d_in[14];
    P.r_b1    = (const float*)d_in[15];
    P.r_W2    = (const float*)d_in[16];
    P.r_b2    = (const float*)d_in[17];
    P.r_Wview = (const float*)d_in[18];
    P.r_bview = (const float*)d_in[19];
    P.r_Wmode = (const float*)d_in[20];
    P.r_bmode = (const float*)d_in[21];
    P.log_tau = (const float*)d_in[22];
    P.L_Wq    = (const float*)d_in[23];
    P.L_Wk    = (const float*)d_in[24];
    P.L_Wv    = (const float*)d_in[25];
    P.L_Wo    = (const float*)d_in[26];
    P.L_ln1g  = (const float*)d_in[27];
    P.L_ln1b  = (const float*)d_in[28];
    P.L_ln2g  = (const float*)d_in[29];
    P.L_ln2b  = (const float*)d_in[30];
    P.L_Wf1   = (const float*)d_in[31];
    P.L_bf1   = (const float*)d_in[32];
    P.L_Wf2   = (const float*)d_in[33];
    P.L_bf2   = (const float*)d_in[34];
    P.p_lng   = (const float*)d_in[35];
    P.p_lnb   = (const float*)d_in[36];
    P.p_W1    = (const float*)d_in[37];
    P.p_b1    = (const float*)d_in[38];
    P.p_W2    = (const float*)d_in[39];
    P.p_b2    = (const float*)d_in[40];
    P.wsf     = (const uint4*)d_ws;
    P.out     = (float*)d_out;
    // prep: 96KB of split-bf16 weight fragments into d_ws (stream-ordered before main)
    hipLaunchKernelGGL(prep_w, dim3(12), dim3(256), 0, stream,
                       P.Wv_emb, P.L_Wk, P.L_Wv, (uint4*)d_ws);
    hipLaunchKernelGGL(gora_fused, dim3(NB), dim3(256), 0, stream, P);
}